// Round 1
// baseline (554.480 us; speedup 1.0000x reference)
//
#include <hip/hip_runtime.h>

// out[b,h,w,i,c] = inputs[b,h,w,i] * u[i,c],  u = beta^2 / rowsum(beta^2)
// B=8 H=128 W=128 D=64 C=16. Output 512 MiB fp32 -> write-BW bound (~90us floor).

#define Dd 64
#define Cc 16

__global__ __launch_bounds__(256) void DS2_62466004353281_kernel(
    const float* __restrict__ inputs,   // [B*H*W*D] = 8388608
    const float* __restrict__ beta,     // [D*C] = 1024
    float* __restrict__ out,            // [B*H*W*D*C] = 134217728
    int n_quads)                        // out float4 count = 33554432
{
    __shared__ float u[Dd * Cc];        // 4 KiB normalized squared weights
    const int t = threadIdx.x;

    // threads 0..63 each compute one row of u
    if (t < Dd) {
        float b2[Cc];
        float s = 0.f;
#pragma unroll
        for (int c = 0; c < Cc; ++c) {
            float b = beta[t * Cc + c];
            b2[c] = b * b;
            s += b2[c];
        }
        float inv = 1.0f / s;
#pragma unroll
        for (int c = 0; c < Cc; ++c) u[t * Cc + c] = b2[c] * inv;
    }
    __syncthreads();

    const float4* __restrict__ u4 = (const float4*)u;
    float4* __restrict__ out4 = (float4*)out;

    const int stride = gridDim.x * blockDim.x;
    for (int idx = blockIdx.x * blockDim.x + t; idx < n_quads; idx += stride) {
        const int elem = idx >> 2;          // input element (b,h,w,i) flat
        const int q    = idx & 3;           // which float4 of the 16 c's
        const int i    = elem & (Dd - 1);   // d index (D=64 divides flat layout)
        const float x  = inputs[elem];      // 4-way lane broadcast, L1-served
        const float4 uu = u4[i * 4 + q];    // LDS float4
        float4 o;
        o.x = x * uu.x;
        o.y = x * uu.y;
        o.z = x * uu.z;
        o.w = x * uu.w;
        out4[idx] = o;                      // coalesced 16B/lane store
    }
}

extern "C" void kernel_launch(void* const* d_in, const int* in_sizes, int n_in,
                              void* d_out, int out_size, void* d_ws, size_t ws_size,
                              hipStream_t stream) {
    const float* inputs = (const float*)d_in[0];
    const float* beta   = (const float*)d_in[1];
    float* out          = (float*)d_out;

    const int n_quads = out_size / 4;   // 33,554,432 float4 stores
    dim3 grid(8192), block(256);        // 16 grid-stride iters/thread
    DS2_62466004353281_kernel<<<grid, block, 0, stream>>>(inputs, beta, out, n_quads);
}